// Round 12
// baseline (2979.070 us; speedup 1.0000x reference)
//
#include <hip/hip_runtime.h>

#define TT 128
#define BB 64
#define HH 1024
#define LL 4
#define NWG 256

typedef _Float16 f16;
typedef __attribute__((ext_vector_type(4))) _Float16 f16x4;
typedef __attribute__((ext_vector_type(8))) _Float16 f16x8;
typedef __attribute__((ext_vector_type(4))) float f32x4;
typedef unsigned long long u64;

// ---------------- persistent device buffers ----------------
// Fragment layout for a [64 rows x 1024 k] fp16 tensor (HW-verified r1/r4/r6/r7):
//   flat = ((rg*32 + ktp)*64 + lane)*8 + e
//   rg = row>>4, ktp = k>>5, lane = ((k>>2)&3)<<4 | (row&15), e = ((k>>4)&1)<<2 | (k&3)
__device__ __align__(16) f16 g_in16[TT][65536];        // inputs, frag layout per t
// 4-deep rotating state slots (t&3); producers publish with device-scope atomic
// stores, mirror fillers read with device-scope atomic loads. (r10-proven)
__device__ __align__(16) f16 g_c16[LL][4][65536];      // cell state (feeds next layer)
__device__ __align__(16) f16 g_h16[LL][4][65536];      // hidden state (U-matmul input)
__device__ __align__(16) float g_c32[LL][BB][HH];      // cell state master f32 (WG-private)
__device__ unsigned g_ep[LL][64];                      // producer epochs (atomic STORE)
// r12: XCD-local mirror, 2-deep region rotation (t&1). Footprint per XCD <= 1.75 MB
// (fits 4 MB L2; r11's 4-deep = 4 MB thrashed: +1.1 GB HBM write-backs, +1 GB fetches).
// Coherence r11-proven: fill = coherent pull from MALL + plain store (dirty in LOCAL
// L2 = always-current for local readers); GEMM = plain loads (L2-hit). L1 staleness:
// >=512 KB distinct lines stream through each 32 KB L1 between region re-fills.
__device__ __align__(16) f16 g_mir[8][LL][2][2][65536];   // 16 MB
__device__ unsigned g_elect[LL][8];                    // ticket counters (runtime XCD map)
__device__ unsigned g_arrive;                          // one-time arrival barrier
__device__ unsigned g_mep[8][LL];                      // monotonic mirror-fill counters

// ---------------- init ----------------
__global__ void k_init() {
  unsigned tid = blockIdx.x * blockDim.x + threadIdx.x;
  unsigned n = gridDim.x * blockDim.x;
  float* c32 = &g_c32[0][0][0];
  for (unsigned i = tid; i < LL * BB * HH; i += n) c32[i] = 0.f;
  for (unsigned i = tid; i < LL * 32768; i += n) {
    int jj = i >> 15, q = i & 32767;
    ((unsigned*)&g_h16[jj][0][0])[q] = 0u;   // h(0) = 0 in slot 0
  }
  unsigned* pe = &g_ep[0][0];
  for (unsigned i = tid; i < LL * 64; i += n) pe[i] = 0u;
  unsigned* pl = &g_elect[0][0];
  for (unsigned i = tid; i < LL * 8; i += n) pl[i] = 0u;
  unsigned* pm = &g_mep[0][0];
  for (unsigned i = tid; i < 8 * LL; i += n) pm[i] = 0u;
  if (tid == 0) g_arrive = 0u;
}

// ---------------- pack inputs f32 -> fp16 fragment layout (verified) ----------------
__global__ void k_pack_in(const float* __restrict__ inp) {
  int tid = blockIdx.x * blockDim.x + threadIdx.x;
  int t = tid >> 14, q = tid & 16383;
  int row = q >> 8, hu = (q & 255) << 2;
  const float4 x = *(const float4*)(inp + ((size_t)t << 16) + (row << 10) + hu);
  int rg = row >> 4, ktp = hu >> 5;
  int ln = (((hu >> 2) & 3) << 4) | (row & 15);
  int e0 = ((hu >> 4) & 1) << 2;
  f16x4 v = {(f16)x.x, (f16)x.y, (f16)x.z, (f16)x.w};
  *(f16x4*)&g_in16[t][(((rg * 32 + ktp) * 64 + ln) << 3) + e0] = v;
}

// ---------------- helpers ----------------
__device__ __forceinline__ float sigf(float x) { return 1.f / (1.f + __expf(-x)); }
__device__ __forceinline__ float tanh_(float x) {
  float q = __expf(-2.f * fabsf(x));
  return copysignf((1.f - q) / (1.f + q), x);
}
__device__ __forceinline__ f16x4 lo8(f16x8 v) { return __builtin_shufflevector(v, v, 0, 1, 2, 3); }
__device__ __forceinline__ f16x4 hi8(f16x8 v) { return __builtin_shufflevector(v, v, 4, 5, 6, 7); }
// coherent (device-scope) 16B state load: bypasses stale L1/L2, reads MALL (r6-proven)
__device__ __forceinline__ f16x8 ldA(const f16* p) {
  const u64* q = (const u64*)p;
  union { u64 v[2]; f16x8 h; } u;
  u.v[0] = __hip_atomic_load(q,     __ATOMIC_RELAXED, __HIP_MEMORY_SCOPE_AGENT);
  u.v[1] = __hip_atomic_load(q + 1, __ATOMIC_RELAXED, __HIP_MEMORY_SCOPE_AGENT);
  return u.h;
}

#define MFMA16(A_, B_, C_) __builtin_amdgcn_mfma_f32_16x16x16f16(A_, B_, C_, 0, 0, 0)
#define SWZ(r) ((((r) & 4) << 2) ^ (((r) & 3) << 3))

// Decomposition (r7/r10-proven): WG (j,s) owns 64 rows x 64 gate-cols; wave w:
// mat = w>>2, kq = w&3, Wr[32] f16x8 weights in regs, disjoint A K-slice.
// Stage: wave0 lane-parallel ep polls -> cooperative mirror fill (coherent pull
// from MALL, plain store to local L2) -> mep handshake -> GEMM with PLAIN loads
// from the XCD mirror (L2-hit) -> LDS reduce -> gates -> coherent publish.
__global__ __launch_bounds__(512, 2) void k_main(const float* __restrict__ W,
                                                 const float* __restrict__ U,
                                                 const float* __restrict__ bias,
                                                 float* __restrict__ out) {
  const int j = blockIdx.x >> 6, s = blockIdx.x & 63;
  const int tid = threadIdx.x, lane = tid & 63, wv = tid >> 6;
  const int mat = wv >> 2, kq = wv & 3;
  __shared__ float zl[16384];  // 64 KiB
  __shared__ unsigned shinfo[2];

  // runtime XCD id (per-WG uniform; robust to any dispatch mapping)
  unsigned xcd;
  asm("s_getreg_b32 %0, hwreg(HW_REG_XCC_ID)" : "=s"(xcd));
  xcd &= 7u;

  // ---- one-time weight gather f32 -> fp16 regs (r4-verified) ----
  const float* src = (mat ? U : W) + (size_t)j * (HH * 4 * HH);
  const int colb = s * 16 + (lane & 15);
  const int kb0 = kq * 256 + ((lane >> 4) << 2);
  f16x8 Wr[32];
#pragma unroll
  for (int kk = 0; kk < 16; ++kk)
#pragma unroll
    for (int cfp = 0; cfp < 2; ++cfp) {
      f16x8 v;
#pragma unroll
      for (int hf = 0; hf < 2; ++hf)
#pragma unroll
        for (int e = 0; e < 4; ++e)
          v[hf * 4 + e] = (f16)src[(size_t)(kb0 + kk * 16 + e) * 4096 + (cfp * 2 + hf) * 1024 + colb];
      Wr[kk * 2 + cfp] = v;
    }

  // ---- one-time election + arrival barrier (all 256 WGs co-resident) ----
  if (tid == 0) {
    unsigned tk = __hip_atomic_fetch_add(&g_elect[j][xcd], 1u,
                                         __ATOMIC_RELAXED, __HIP_MEMORY_SCOPE_AGENT);
    __hip_atomic_fetch_add(&g_arrive, 1u, __ATOMIC_RELAXED, __HIP_MEMORY_SCOPE_AGENT);
    while (__hip_atomic_load(&g_arrive, __ATOMIC_RELAXED, __HIP_MEMORY_SCOPE_AGENT) < NWG)
      __builtin_amdgcn_s_sleep(2);
    shinfo[0] = tk;
    shinfo[1] = __hip_atomic_load(&g_elect[j][xcd], __ATOMIC_RELAXED, __HIP_MEMORY_SCOPE_AGENT);
  }
  __syncthreads();
  const unsigned ticket = shinfo[0], nfill = shinfo[1];

  // ---- per-thread epilogue constants (r10-verified) ----
  const bool act = tid < 256;
  const int row = (tid & 255) >> 2;
  const int hl0q = (tid & 3) * 4;
  const int hu0 = s * 16 + hl0q;
  f32x4 brg[4];
#pragma unroll
  for (int g = 0; g < 4; ++g) brg[g] = *(const f32x4*)&bias[j * 4096 + g * 1024 + hu0];
  const int grp = (((row >> 4) * 32 + (hu0 >> 5)) * 64 +
                   ((((hu0 >> 2) & 3) << 4) | (row & 15)));
  const int e0 = ((hu0 >> 4) & 1) << 2;
  const int g64 = grp * 2 + (e0 >> 2);
  u64* const hP = (u64*)&g_h16[j][0][0];
  u64* const cP = (u64*)&g_c16[j][0][0];
  float* const c32p = &g_c32[j][row][hu0];
  const int ktp0 = kq * 8;

  for (int t = 0; t < TT; ++t) {
    const int rs = t & 1;       // mirror region (2-deep)

    // ---- stage-top dependency polls: wave 0, lane l polls producer l ----
    if (wv == 0) {
      const bool nx = (j > 0), nh = (t > 0), na = (j < 3 && t >= 2);
      if (nx | nh | na) {
        for (;;) {
          bool ok = true;
          if (nx) ok &= (__hip_atomic_load(&g_ep[j - 1][lane], __ATOMIC_RELAXED,
                                           __HIP_MEMORY_SCOPE_AGENT) >= (unsigned)(t + 1));
          if (nh) ok &= (__hip_atomic_load(&g_ep[j][lane], __ATOMIC_RELAXED,
                                           __HIP_MEMORY_SCOPE_AGENT) >= (unsigned)t);
          if (na) ok &= (__hip_atomic_load(&g_ep[j + 1][lane], __ATOMIC_RELAXED,
                                           __HIP_MEMORY_SCOPE_AGENT) >= (unsigned)(t - 2));
          if (__all((int)ok)) break;
          __builtin_amdgcn_s_sleep(1);
        }
      }
    }
    __syncthreads();

    // ---- cooperative mirror fill: slices k == ticket (mod nfill), 16 KB each ----
    {
      f16* const mbase = &g_mir[xcd][j][rs][0][0];
      for (unsigned k = ticket; k < 16u; k += nfill) {
        if (j == 0 && k < 8u) continue;          // layer 0: x comes from in16 directly
        const int mk = (int)(k >> 3), sub = (int)(k & 7);
        const f16* sp = (mk ? &g_h16[j][t & 3][0] : &g_c16[j - 1][(t + 1) & 3][0])
                        + sub * 8192 + tid * 16;
        f16* dp = mbase + mk * 65536 + sub * 8192 + tid * 16;
        f16x8 v0 = ldA(sp), v1 = ldA(sp + 8);    // coherent pull from MALL
        *(f16x8*)dp = v0;                        // plain store -> local L2 (dirty)
        *(f16x8*)(dp + 8) = v1;
      }
    }
    asm volatile("s_waitcnt vmcnt(0)" ::: "memory");  // fills visible in L2
    __syncthreads();
    if (tid == 0) {
      __hip_atomic_fetch_add(&g_mep[xcd][j], 1u, __ATOMIC_RELAXED, __HIP_MEMORY_SCOPE_AGENT);
      while (__hip_atomic_load(&g_mep[xcd][j], __ATOMIC_RELAXED,
                               __HIP_MEMORY_SCOPE_AGENT) < nfill * (unsigned)(t + 1))
        __builtin_amdgcn_s_sleep(1);
    }
    __syncthreads();

    // ---- GEMM: A via PLAIN loads from the XCD-local mirror (L2-hit) ----
    const f16* Ab = mat ? &g_mir[xcd][j][rs][1][0]
                        : (j ? &g_mir[xcd][j][rs][0][0] : &g_in16[t][0]);
    f16x8 a[2][4];
#pragma unroll
    for (int rf = 0; rf < 4; ++rf)
      a[0][rf] = *(const f16x8*)(Ab + (rf * 32 + ktp0) * 512 + lane * 8);

    f32x4 acc[4][4];
#pragma unroll
    for (int rf = 0; rf < 4; ++rf)
#pragma unroll
      for (int cf = 0; cf < 4; ++cf) acc[rf][cf] = (f32x4){0.f, 0.f, 0.f, 0.f};

#pragma unroll
    for (int kc = 0; kc < 8; ++kc) {
      if (kc < 7) {
#pragma unroll
        for (int rf = 0; rf < 4; ++rf)
          a[(kc + 1) & 1][rf] = *(const f16x8*)(Ab + (rf * 32 + ktp0 + kc + 1) * 512 + lane * 8);
      }
#pragma unroll
      for (int hf = 0; hf < 2; ++hf) {
        f16x4 a4[4];
#pragma unroll
        for (int rf = 0; rf < 4; ++rf)
          a4[rf] = hf ? hi8(a[kc & 1][rf]) : lo8(a[kc & 1][rf]);
#pragma unroll
        for (int cf = 0; cf < 4; ++cf) {
          const f16x8 wreg = Wr[(kc * 2 + hf) * 2 + (cf >> 1)];
          const f16x4 b4 = (cf & 1) ? hi8(wreg) : lo8(wreg);
#pragma unroll
          for (int rf = 0; rf < 4; ++rf) acc[rf][cf] = MFMA16(a4[rf], b4, acc[rf][cf]);
        }
      }
    }

    // ---- 8-wave reduction via 64 KiB LDS, two column-phases (r10-verified) ----
    float gsum[4][4];
#pragma unroll
    for (int P = 0; P < 2; ++P) {
      __syncthreads();
#pragma unroll
      for (int rf = 0; rf < 4; ++rf)
#pragma unroll
        for (int ch = 0; ch < 2; ++ch) {
          const int cf = P * 2 + ch;
#pragma unroll
          for (int ri = 0; ri < 4; ++ri) {
            const int rr = rf * 16 + ((lane >> 4) << 2) + ri;
            const int c2 = ch * 16 + (lane & 15);
            zl[wv * 2048 + rr * 32 + (c2 ^ SWZ(rr))] = acc[rf][cf][ri];
          }
        }
      __syncthreads();
      if (act) {
#pragma unroll
        for (int ch = 0; ch < 2; ++ch) {
          const int g = P * 2 + ch;
          const int swcol = (ch * 16 + hl0q) ^ SWZ(row);
          f32x4 ss = (f32x4){0.f, 0.f, 0.f, 0.f};
#pragma unroll
          for (int w = 0; w < 8; ++w) ss += *(const f32x4*)&zl[w * 2048 + row * 32 + swcol];
#pragma unroll
          for (int el = 0; el < 4; ++el) gsum[el][g] = ss[el];
        }
      }
    }

    // ---- gates + state update (i,f,g,o); 8B coherent publish (r10-verified) ----
    if (act) {
      const f32x4 cp = *(const f32x4*)c32p;
      f32x4 cn, hn;
#pragma unroll
      for (int el = 0; el < 4; ++el) {
        const float zi = gsum[el][0] + brg[0][el];
        const float zf = gsum[el][1] + brg[1][el];
        const float zg = gsum[el][2] + brg[2][el];
        const float zo = gsum[el][3] + brg[3][el];
        cn[el] = sigf(zf) * cp[el] + sigf(zi) * tanh_(zg);
        hn[el] = sigf(zo) * tanh_(cn[el]);
      }
      *(f32x4*)c32p = cn;
      union { f16 h[4]; u64 u; } ph, pc;
#pragma unroll
      for (int el = 0; el < 4; ++el) { ph.h[el] = (f16)hn[el]; pc.h[el] = (f16)cn[el]; }
      const int slot = (t + 1) & 3;
      __hip_atomic_store(hP + (size_t)slot * 16384 + g64, ph.u,
                         __ATOMIC_RELAXED, __HIP_MEMORY_SCOPE_AGENT);
      if (j < 3)
        __hip_atomic_store(cP + (size_t)slot * 16384 + g64, pc.u,
                           __ATOMIC_RELAXED, __HIP_MEMORY_SCOPE_AGENT);
      if (j == 3 && t == TT - 1) *(f32x4*)&out[(row << 10) + hu0] = cn;
    }

    // ---- publish: drain device-scope stores, barrier, epoch STORE ----
    asm volatile("s_waitcnt vmcnt(0)" ::: "memory");
    __syncthreads();
    if (tid == 0)
      __hip_atomic_store(&g_ep[j][s], (unsigned)(t + 1),
                         __ATOMIC_RELAXED, __HIP_MEMORY_SCOPE_AGENT);
  }
}

extern "C" void kernel_launch(void* const* d_in, const int* in_sizes, int n_in,
                              void* d_out, int out_size, void* d_ws, size_t ws_size,
                              hipStream_t stream) {
  const float* inp  = (const float*)d_in[0];
  const float* W    = (const float*)d_in[1];
  const float* U    = (const float*)d_in[2];
  const float* bias = (const float*)d_in[3];
  float* out = (float*)d_out;
  k_init<<<256, 256, 0, stream>>>();
  k_pack_in<<<4096, 512, 0, stream>>>(inp);
  k_main<<<NWG, 512, 0, stream>>>(W, U, bias, out);
}

// Round 13
// 2637.754 us; speedup vs baseline: 1.1294x; 1.1294x over previous
//
#include <hip/hip_runtime.h>

#define TT 128
#define BB 64
#define HH 1024
#define LL 4
#define NWG 256

typedef _Float16 f16;
typedef __attribute__((ext_vector_type(4))) _Float16 f16x4;
typedef __attribute__((ext_vector_type(8))) _Float16 f16x8;
typedef __attribute__((ext_vector_type(4))) float f32x4;
typedef unsigned long long u64;

// ---------------- persistent device buffers ----------------
// Fragment layout for a [64 rows x 1024 k] fp16 tensor (HW-verified r1/r4/r6/r7):
//   flat = ((rg*32 + ktp)*64 + lane)*8 + e
//   rg = row>>4, ktp = k>>5, lane = ((k>>2)&3)<<4 | (row&15), e = ((k>>4)&1)<<2 | (k&3)
__device__ __align__(16) f16 g_in16[TT][65536];        // inputs, frag layout per t
// 4-deep rotating state slots (t&3); producers publish with device-scope atomic
// stores, consumers read with device-scope atomic loads (bypass stale L1/L2).
// NO cache-wide fences anywhere. (r10-proven best structure, 2120 us)
__device__ __align__(16) f16 g_c16[LL][4][65536];      // cell state (feeds next layer)
__device__ __align__(16) f16 g_h16[LL][4][65536];      // hidden state (U-matmul input)
__device__ __align__(16) float g_c32[LL][BB][HH];      // cell state master f32 (WG-private)
// per-producer epoch: g_ep[j][s] = t+1 after WG (j,s) finished step t (atomic STORE).
__device__ unsigned g_ep[LL][64];

// ---------------- init: zero h slot 0 + epochs + c32 ----------------
__global__ void k_init() {
  unsigned tid = blockIdx.x * blockDim.x + threadIdx.x;
  unsigned n = gridDim.x * blockDim.x;
  float* c32 = &g_c32[0][0][0];
  for (unsigned i = tid; i < LL * BB * HH; i += n) c32[i] = 0.f;
  for (unsigned i = tid; i < LL * 32768; i += n) {
    int jj = i >> 15, q = i & 32767;
    ((unsigned*)&g_h16[jj][0][0])[q] = 0u;   // h(0) = 0 in slot 0
  }
  unsigned* pe = &g_ep[0][0];
  for (unsigned i = tid; i < LL * 64; i += n) pe[i] = 0u;
}

// ---------------- pack inputs f32 -> fp16 fragment layout (verified) ----------------
__global__ void k_pack_in(const float* __restrict__ inp) {
  int tid = blockIdx.x * blockDim.x + threadIdx.x;
  int t = tid >> 14, q = tid & 16383;
  int row = q >> 8, hu = (q & 255) << 2;
  const float4 x = *(const float4*)(inp + ((size_t)t << 16) + (row << 10) + hu);
  int rg = row >> 4, ktp = hu >> 5;
  int ln = (((hu >> 2) & 3) << 4) | (row & 15);
  int e0 = ((hu >> 4) & 1) << 2;
  f16x4 v = {(f16)x.x, (f16)x.y, (f16)x.z, (f16)x.w};
  *(f16x4*)&g_in16[t][(((rg * 32 + ktp) * 64 + ln) << 3) + e0] = v;
}

// ---------------- helpers ----------------
__device__ __forceinline__ float sigf(float x) { return 1.f / (1.f + __expf(-x)); }
__device__ __forceinline__ float tanh_(float x) {
  float q = __expf(-2.f * fabsf(x));
  return copysignf((1.f - q) / (1.f + q), x);
}
__device__ __forceinline__ f16x4 lo8(f16x8 v) { return __builtin_shufflevector(v, v, 0, 1, 2, 3); }
__device__ __forceinline__ f16x4 hi8(f16x8 v) { return __builtin_shufflevector(v, v, 4, 5, 6, 7); }
// lane-parallel wait: lane l polls its own producer-epoch slot; exit when all >= target
__device__ __forceinline__ void waitep(const unsigned* ep, unsigned target) {
  for (;;) {
    unsigned e = __hip_atomic_load(ep, __ATOMIC_RELAXED, __HIP_MEMORY_SCOPE_AGENT);
    if (__all((int)(e >= target))) break;
    __builtin_amdgcn_s_sleep(1);
  }
}
// coherent (device-scope) 16B state load: two u64 atomic loads, bypass stale L1/L2,
// vmcnt-tracked by the compiler (pipelines normally). coh is wave-uniform. (r6-proven)
__device__ __forceinline__ f16x8 ldA(const f16* p, bool coh) {
  if (coh) {
    const u64* q = (const u64*)p;
    union { u64 v[2]; f16x8 h; } u;
    u.v[0] = __hip_atomic_load(q,     __ATOMIC_RELAXED, __HIP_MEMORY_SCOPE_AGENT);
    u.v[1] = __hip_atomic_load(q + 1, __ATOMIC_RELAXED, __HIP_MEMORY_SCOPE_AGENT);
    return u.h;
  }
  return *(const f16x8*)p;
}

#define MFMA16(A_, B_, C_) __builtin_amdgcn_mfma_f32_16x16x16f16(A_, B_, C_, 0, 0, 0)
#define SWZ(r) ((((r) & 4) << 2) ^ (((r) & 3) << 3))

// Decomposition (r7/r10-proven): WG (j,s) owns 64 rows x 64 gate-cols. Wave w:
// mat = w>>2 (0: x@W, 1: h@U), K-quarter kq = w&3; Wr[32] f16x8 = 128 VGPRs,
// disjoint 32 KB A slice. 8 partials reduced via 64 KiB LDS (two col-phases).
// r13: depth-3 ring-4 A prefetch (12 coherent loads in flight; unified-file budget
// 128 Wr + 64 a-ring + 64 AGPR acc = 256) to break MALL RTT serialization.
__global__ __launch_bounds__(512, 2) void k_main(const float* __restrict__ W,
                                                 const float* __restrict__ U,
                                                 const float* __restrict__ bias,
                                                 float* __restrict__ out) {
  const int j = blockIdx.x >> 6, s = blockIdx.x & 63;
  const int tid = threadIdx.x, lane = tid & 63, wv = tid >> 6;
  const int mat = wv >> 2, kq = wv & 3;
  __shared__ float zl[16384];  // [8 waves][64 rows][32 colhalf], swizzled, 64 KiB

  // ---- one-time weight gather f32 -> fp16 regs (r4-verified) ----
  const float* src = (mat ? U : W) + (size_t)j * (HH * 4 * HH);
  const int colb = s * 16 + (lane & 15);
  const int kb0 = kq * 256 + ((lane >> 4) << 2);
  f16x8 Wr[32];
#pragma unroll
  for (int kk = 0; kk < 16; ++kk)
#pragma unroll
    for (int cfp = 0; cfp < 2; ++cfp) {
      f16x8 v;
#pragma unroll
      for (int hf = 0; hf < 2; ++hf)
#pragma unroll
        for (int e = 0; e < 4; ++e)
          v[hf * 4 + e] = (f16)src[(size_t)(kb0 + kk * 16 + e) * 4096 + (cfp * 2 + hf) * 1024 + colb];
      Wr[kk * 2 + cfp] = v;
    }

  // ---- per-thread epilogue constants (r10-verified) ----
  const bool act = tid < 256;
  const int row = (tid & 255) >> 2;        // 0..63
  const int hl0q = (tid & 3) * 4;          // 0,4,8,12
  const int hu0 = s * 16 + hl0q;           // 4-aligned
  f32x4 brg[4];
#pragma unroll
  for (int g = 0; g < 4; ++g) brg[g] = *(const f32x4*)&bias[j * 4096 + g * 1024 + hu0];
  const int grp = (((row >> 4) * 32 + (hu0 >> 5)) * 64 +
                   ((((hu0 >> 2) & 3) << 4) | (row & 15)));
  const int e0 = ((hu0 >> 4) & 1) << 2;
  const int g64 = grp * 2 + (e0 >> 2);     // u64 index within a slot (slot = 16384 u64)
  u64* const hP = (u64*)&g_h16[j][0][0];
  u64* const cP = (u64*)&g_c16[j][0][0];
  float* const c32p = &g_c32[j][row][hu0];
  const int ktp0 = kq * 8;
  const bool coh = mat || (j > 0);  // in16 is pre-launch constant -> plain loads ok
  const unsigned* epX = (j > 0) ? &g_ep[j - 1][kq * 16 + (lane & 15)] : nullptr;
  const unsigned* epH = &g_ep[j][kq * 16 + (lane & 15)];
  const unsigned* epA = (j < 3) ? &g_ep[j + 1][lane] : nullptr;  // anti-overwrite, 64-wide

  for (int t = 0; t < TT; ++t) {
    // ---- per-wave dependency waits (no fences, no RMW flags; r10-proven) ----
    if (mat == 0) {
      if (j > 0) waitep(epX, (unsigned)(t + 1));       // layer below finished step t
    } else {
      if (t > 0) waitep(epH, (unsigned)t);             // own layer finished step t-1
      if (j < 3 && t >= 2) waitep(epA, (unsigned)(t - 2));  // slot-reuse: consumers done
    }
    asm volatile("" ::: "memory");  // forbid hoisting A loads above the polls

    const f16* Ab = mat ? &g_h16[j][t & 3][0]
                        : (j ? &g_c16[j - 1][(t + 1) & 3][0] : &g_in16[t][0]);

    // ---- depth-3 ring-4 prefetch: 12 coherent loads in flight ----
    f16x8 a[4][4];
#pragma unroll
    for (int pk = 0; pk < 3; ++pk)
#pragma unroll
      for (int rf = 0; rf < 4; ++rf)
        a[pk][rf] = ldA(Ab + (rf * 32 + ktp0 + pk) * 512 + lane * 8, coh);

    f32x4 acc[4][4];
#pragma unroll
    for (int rf = 0; rf < 4; ++rf)
#pragma unroll
      for (int cf = 0; cf < 4; ++cf) acc[rf][cf] = (f32x4){0.f, 0.f, 0.f, 0.f};

#pragma unroll
    for (int kc = 0; kc < 8; ++kc) {
      if (kc < 5) {
#pragma unroll
        for (int rf = 0; rf < 4; ++rf)
          a[(kc + 3) & 3][rf] = ldA(Ab + (rf * 32 + ktp0 + kc + 3) * 512 + lane * 8, coh);
      }
#pragma unroll
      for (int hf = 0; hf < 2; ++hf) {
        f16x4 a4[4];
#pragma unroll
        for (int rf = 0; rf < 4; ++rf)
          a4[rf] = hf ? hi8(a[kc & 3][rf]) : lo8(a[kc & 3][rf]);
#pragma unroll
        for (int cf = 0; cf < 4; ++cf) {
          const f16x8 wreg = Wr[(kc * 2 + hf) * 2 + (cf >> 1)];
          const f16x4 b4 = (cf & 1) ? hi8(wreg) : lo8(wreg);
#pragma unroll
          for (int rf = 0; rf < 4; ++rf) acc[rf][cf] = MFMA16(a4[rf], b4, acc[rf][cf]);
        }
      }
    }

    // ---- 8-wave reduction via 64 KiB LDS, two column-phases (r10-verified) ----
    float gsum[4][4];  // [el 0..3][gate]
#pragma unroll
    for (int P = 0; P < 2; ++P) {
      __syncthreads();  // joins x/h waves; protects zl reuse vs previous phase/step
#pragma unroll
      for (int rf = 0; rf < 4; ++rf)
#pragma unroll
        for (int ch = 0; ch < 2; ++ch) {
          const int cf = P * 2 + ch;
#pragma unroll
          for (int ri = 0; ri < 4; ++ri) {
            const int rr = rf * 16 + ((lane >> 4) << 2) + ri;
            const int c2 = ch * 16 + (lane & 15);
            zl[wv * 2048 + rr * 32 + (c2 ^ SWZ(rr))] = acc[rf][cf][ri];
          }
        }
      __syncthreads();
      if (act) {
#pragma unroll
        for (int ch = 0; ch < 2; ++ch) {
          const int g = P * 2 + ch;
          const int swcol = (ch * 16 + hl0q) ^ SWZ(row);  // 4-aligned (SWZ hits bits 3-4)
          f32x4 ss = (f32x4){0.f, 0.f, 0.f, 0.f};
#pragma unroll
          for (int w = 0; w < 8; ++w) ss += *(const f32x4*)&zl[w * 2048 + row * 32 + swcol];
#pragma unroll
          for (int el = 0; el < 4; ++el) gsum[el][P * 2 + ch] = ss[el];
        }
      }
    }

    // ---- gates + state update (i,f,g,o); 8B coherent publish (r10-verified) ----
    if (act) {
      const f32x4 cp = *(const f32x4*)c32p;
      f32x4 cn, hn;
#pragma unroll
      for (int el = 0; el < 4; ++el) {
        const float zi = gsum[el][0] + brg[0][el];
        const float zf = gsum[el][1] + brg[1][el];
        const float zg = gsum[el][2] + brg[2][el];
        const float zo = gsum[el][3] + brg[3][el];
        cn[el] = sigf(zf) * cp[el] + sigf(zi) * tanh_(zg);
        hn[el] = sigf(zo) * tanh_(cn[el]);
      }
      *(f32x4*)c32p = cn;
      union { f16 h[4]; u64 u; } ph, pc;
#pragma unroll
      for (int el = 0; el < 4; ++el) { ph.h[el] = (f16)hn[el]; pc.h[el] = (f16)cn[el]; }
      const int slot = (t + 1) & 3;
      __hip_atomic_store(hP + (size_t)slot * 16384 + g64, ph.u,
                         __ATOMIC_RELAXED, __HIP_MEMORY_SCOPE_AGENT);
      if (j < 3)
        __hip_atomic_store(cP + (size_t)slot * 16384 + g64, pc.u,
                           __ATOMIC_RELAXED, __HIP_MEMORY_SCOPE_AGENT);
      if (j == 3 && t == TT - 1) *(f32x4*)&out[(row << 10) + hu0] = cn;
    }

    // ---- publish: drain device-scope stores, barrier, single epoch STORE ----
    asm volatile("s_waitcnt vmcnt(0)" ::: "memory");
    __syncthreads();
    if (tid == 0)
      __hip_atomic_store(&g_ep[j][s], (unsigned)(t + 1),
                         __ATOMIC_RELAXED, __HIP_MEMORY_SCOPE_AGENT);
  }
}

extern "C" void kernel_launch(void* const* d_in, const int* in_sizes, int n_in,
                              void* d_out, int out_size, void* d_ws, size_t ws_size,
                              hipStream_t stream) {
  const float* inp  = (const float*)d_in[0];
  const float* W    = (const float*)d_in[1];
  const float* U    = (const float*)d_in[2];
  const float* bias = (const float*)d_in[3];
  float* out = (float*)d_out;
  k_init<<<256, 256, 0, stream>>>();
  k_pack_in<<<4096, 512, 0, stream>>>(inp);
  k_main<<<NWG, 512, 0, stream>>>(W, U, bias, out);
}

// Round 14
// 2408.101 us; speedup vs baseline: 1.2371x; 1.0954x over previous
//
#include <hip/hip_runtime.h>

#define TT 128
#define BB 64
#define HH 1024
#define LL 4
#define NWG 256

typedef _Float16 f16;
typedef __attribute__((ext_vector_type(4))) _Float16 f16x4;
typedef __attribute__((ext_vector_type(8))) _Float16 f16x8;
typedef __attribute__((ext_vector_type(4))) float f32x4;
typedef unsigned long long u64;
typedef __attribute__((address_space(1))) const unsigned int AS1u32;
typedef __attribute__((address_space(3))) unsigned int AS3u32;

// ---------------- persistent device buffers ----------------
// Fragment layout for a [64 rows x 1024 k] fp16 tensor (HW-verified r1/r4/r6/r7):
//   flat = ((rg*32 + ktp)*64 + lane)*8 + e
//   rg = row>>4, ktp = k>>5, lane = ((k>>2)&3)<<4 | (row&15), e = ((k>>4)&1)<<2 | (k&3)
__device__ __align__(16) f16 g_in16[TT][65536];        // inputs, frag layout per t
// 4-deep rotating state slots (t&3); producers publish with device-scope atomic
// stores, consumers read with device-scope (SC0) loads. NO cache-wide fences. (r10)
__device__ __align__(16) f16 g_c16[LL][4][65536];      // cell state (feeds next layer)
__device__ __align__(16) f16 g_h16[LL][4][65536];      // hidden state (U-matmul input)
__device__ __align__(16) float g_c32[LL][BB][HH];      // cell state master f32 (WG-private)
__device__ unsigned g_ep[LL][64];                      // producer epochs (atomic STORE)

// ---------------- init: zero h slot 0 + epochs + c32 ----------------
__global__ void k_init() {
  unsigned tid = blockIdx.x * blockDim.x + threadIdx.x;
  unsigned n = gridDim.x * blockDim.x;
  float* c32 = &g_c32[0][0][0];
  for (unsigned i = tid; i < LL * BB * HH; i += n) c32[i] = 0.f;
  for (unsigned i = tid; i < LL * 32768; i += n) {
    int jj = i >> 15, q = i & 32767;
    ((unsigned*)&g_h16[jj][0][0])[q] = 0u;   // h(0) = 0 in slot 0
  }
  unsigned* pe = &g_ep[0][0];
  for (unsigned i = tid; i < LL * 64; i += n) pe[i] = 0u;
}

// ---------------- pack inputs f32 -> fp16 fragment layout (verified) ----------------
__global__ void k_pack_in(const float* __restrict__ inp) {
  int tid = blockIdx.x * blockDim.x + threadIdx.x;
  int t = tid >> 14, q = tid & 16383;
  int row = q >> 8, hu = (q & 255) << 2;
  const float4 x = *(const float4*)(inp + ((size_t)t << 16) + (row << 10) + hu);
  int rg = row >> 4, ktp = hu >> 5;
  int ln = (((hu >> 2) & 3) << 4) | (row & 15);
  int e0 = ((hu >> 4) & 1) << 2;
  f16x4 v = {(f16)x.x, (f16)x.y, (f16)x.z, (f16)x.w};
  *(f16x4*)&g_in16[t][(((rg * 32 + ktp) * 64 + ln) << 3) + e0] = v;
}

// ---------------- helpers ----------------
__device__ __forceinline__ float sigf(float x) { return 1.f / (1.f + __expf(-x)); }
__device__ __forceinline__ float tanh_(float x) {
  float q = __expf(-2.f * fabsf(x));
  return copysignf((1.f - q) / (1.f + q), x);
}
__device__ __forceinline__ f16x4 lo8(f16x8 v) { return __builtin_shufflevector(v, v, 0, 1, 2, 3); }
__device__ __forceinline__ f16x4 hi8(f16x8 v) { return __builtin_shufflevector(v, v, 4, 5, 6, 7); }
__device__ __forceinline__ void waitep(const unsigned* ep, unsigned target) {
  for (;;) {
    unsigned e = __hip_atomic_load(ep, __ATOMIC_RELAXED, __HIP_MEMORY_SCOPE_AGENT);
    if (__all((int)(e >= target))) break;
    __builtin_amdgcn_s_sleep(1);
  }
}

#define MFMA16(A_, B_, C_) __builtin_amdgcn_mfma_f32_16x16x16f16(A_, B_, C_, 0, 0, 0)
#define SWZ(r) ((((r) & 4) << 2) ^ (((r) & 3) << 3))

// r14 GEMM core: per-wave 3-chunk LDS DMA ring (zero VGPR cost, counted vmcnt).
// AUX: cpol for global_load_lds — 1 (SC0, agent-coherent, bypass stale L1/L2) for
// state; 0 (cached) for the immutable g_in16. Ring chunk = one kc (4 rf x 1 KB).
// vmcnt budget: issued(kc)=12+4*min(kc,5), consumed=4(kc+1) -> 8,8,8,8,8,8,4,0.
template <int AUX>
__device__ __forceinline__ void gemm_stage(const f16* Ab, f16* rb, const f16x8 (&Wr)[32],
                                           f32x4 (&acc)[4][4], int ktp0, int lane) {
#pragma unroll
  for (int pk = 0; pk < 3; ++pk)
#pragma unroll
    for (int rf = 0; rf < 4; ++rf)
      __builtin_amdgcn_global_load_lds(
          (AS1u32*)(const void*)(Ab + (rf * 32 + ktp0 + pk) * 512 + lane * 8),
          (AS3u32*)(void*)(rb + pk * 2048 + rf * 512), 16, 0, AUX);
#pragma unroll
  for (int kc = 0; kc < 8; ++kc) {
    if (kc < 6)       asm volatile("s_waitcnt vmcnt(8)" ::: "memory");
    else if (kc == 6) asm volatile("s_waitcnt vmcnt(4)" ::: "memory");
    else              asm volatile("s_waitcnt vmcnt(0)" ::: "memory");
    f16x8 av[4];
#pragma unroll
    for (int rf = 0; rf < 4; ++rf)
      av[rf] = *(const f16x8*)(rb + (kc % 3) * 2048 + rf * 512 + lane * 8);
#pragma unroll
    for (int hf = 0; hf < 2; ++hf) {
      f16x4 a4[4];
#pragma unroll
      for (int rf = 0; rf < 4; ++rf) a4[rf] = hf ? hi8(av[rf]) : lo8(av[rf]);
#pragma unroll
      for (int cf = 0; cf < 4; ++cf) {
        const f16x8 wreg = Wr[(kc * 2 + hf) * 2 + (cf >> 1)];
        const f16x4 b4 = (cf & 1) ? hi8(wreg) : lo8(wreg);
#pragma unroll
        for (int rf = 0; rf < 4; ++rf) acc[rf][cf] = MFMA16(a4[rf], b4, acc[rf][cf]);
      }
    }
    if (kc < 5) {  // issue chunk kc+3 into slot (kc+3)%3 == kc%3 (just consumed)
#pragma unroll
      for (int rf = 0; rf < 4; ++rf)
        __builtin_amdgcn_global_load_lds(
            (AS1u32*)(const void*)(Ab + (rf * 32 + ktp0 + kc + 3) * 512 + lane * 8),
            (AS3u32*)(void*)(rb + (kc % 3) * 2048 + rf * 512), 16, 0, AUX);
    }
  }
}

// Decomposition (r7/r10-proven): WG (j,s) owns 64 rows x 64 gate-cols. Wave w:
// mat = w>>2 (0: x@W, 1: h@U), K-quarter kq = w&3; Wr[32] f16x8 = 128 VGPRs,
// disjoint 32 KB A slice streamed via LDS DMA ring. 8 partials reduced via zl.
// LDS: 96 KiB union — ring[8 waves][12 KiB] during GEMM, zl 64 KiB during reduce
// (temporally disjoint: reduce entry barrier follows per-wave vmcnt(0); publish
// barrier drains zl reads before next stage's prologue).
__global__ __launch_bounds__(512, 2) void k_main(const float* __restrict__ W,
                                                 const float* __restrict__ U,
                                                 const float* __restrict__ bias,
                                                 float* __restrict__ out) {
  const int j = blockIdx.x >> 6, s = blockIdx.x & 63;
  const int tid = threadIdx.x, lane = tid & 63, wv = tid >> 6;
  const int mat = wv >> 2, kq = wv & 3;
  __shared__ __align__(16) unsigned char ldsbuf[98304];  // 96 KiB (ring ∪ zl)
  float* const zl = (float*)ldsbuf;
  f16* const rb = (f16*)ldsbuf + wv * 6144;  // per-wave ring: 3 x 4 KiB chunks

  // ---- one-time weight gather f32 -> fp16 regs (r4-verified) ----
  const float* src = (mat ? U : W) + (size_t)j * (HH * 4 * HH);
  const int colb = s * 16 + (lane & 15);
  const int kb0 = kq * 256 + ((lane >> 4) << 2);
  f16x8 Wr[32];
#pragma unroll
  for (int kk = 0; kk < 16; ++kk)
#pragma unroll
    for (int cfp = 0; cfp < 2; ++cfp) {
      f16x8 v;
#pragma unroll
      for (int hf = 0; hf < 2; ++hf)
#pragma unroll
        for (int e = 0; e < 4; ++e)
          v[hf * 4 + e] = (f16)src[(size_t)(kb0 + kk * 16 + e) * 4096 + (cfp * 2 + hf) * 1024 + colb];
      Wr[kk * 2 + cfp] = v;
    }

  // ---- per-thread epilogue constants (r10-verified) ----
  const bool act = tid < 256;
  const int row = (tid & 255) >> 2;        // 0..63
  const int hl0q = (tid & 3) * 4;          // 0,4,8,12
  const int hu0 = s * 16 + hl0q;           // 4-aligned
  f32x4 brg[4];
#pragma unroll
  for (int g = 0; g < 4; ++g) brg[g] = *(const f32x4*)&bias[j * 4096 + g * 1024 + hu0];
  const int grp = (((row >> 4) * 32 + (hu0 >> 5)) * 64 +
                   ((((hu0 >> 2) & 3) << 4) | (row & 15)));
  const int e0 = ((hu0 >> 4) & 1) << 2;
  const int g64 = grp * 2 + (e0 >> 2);     // u64 index within a slot (slot = 16384 u64)
  u64* const hP = (u64*)&g_h16[j][0][0];
  u64* const cP = (u64*)&g_c16[j][0][0];
  float* const c32p = &g_c32[j][row][hu0];
  const int ktp0 = kq * 8;
  const bool coh = mat || (j > 0);  // in16 is pre-launch constant -> cached DMA ok
  const unsigned* epX = (j > 0) ? &g_ep[j - 1][kq * 16 + (lane & 15)] : nullptr;
  const unsigned* epH = &g_ep[j][kq * 16 + (lane & 15)];
  const unsigned* epA = (j < 3) ? &g_ep[j + 1][lane] : nullptr;  // anti-overwrite

  for (int t = 0; t < TT; ++t) {
    // ---- per-wave dependency waits (no fences, no RMW flags; r10-proven) ----
    if (mat == 0) {
      if (j > 0) waitep(epX, (unsigned)(t + 1));       // layer below finished step t
    } else {
      if (t > 0) waitep(epH, (unsigned)t);             // own layer finished step t-1
      if (j < 3 && t >= 2) waitep(epA, (unsigned)(t - 2));  // slot-reuse: readers done
    }
    asm volatile("" ::: "memory");  // forbid hoisting DMA issues above the polls

    const f16* Ab = mat ? &g_h16[j][t & 3][0]
                        : (j ? &g_c16[j - 1][(t + 1) & 3][0] : &g_in16[t][0]);

    f32x4 acc[4][4];
#pragma unroll
    for (int rf = 0; rf < 4; ++rf)
#pragma unroll
      for (int cf = 0; cf < 4; ++cf) acc[rf][cf] = (f32x4){0.f, 0.f, 0.f, 0.f};

    if (coh) gemm_stage<1>(Ab, rb, Wr, acc, ktp0, lane);
    else     gemm_stage<0>(Ab, rb, Wr, acc, ktp0, lane);

    // ---- 8-wave reduction via zl (64 KiB of the union), two column-phases ----
    float gsum[4][4];  // [el 0..3][gate]
#pragma unroll
    for (int P = 0; P < 2; ++P) {
      __syncthreads();  // joins all waves (each drained its DMAs via vmcnt(0) at kc=7)
#pragma unroll
      for (int rf = 0; rf < 4; ++rf)
#pragma unroll
        for (int ch = 0; ch < 2; ++ch) {
          const int cf = P * 2 + ch;
#pragma unroll
          for (int ri = 0; ri < 4; ++ri) {
            const int rr = rf * 16 + ((lane >> 4) << 2) + ri;
            const int c2 = ch * 16 + (lane & 15);
            zl[wv * 2048 + rr * 32 + (c2 ^ SWZ(rr))] = acc[rf][cf][ri];
          }
        }
      __syncthreads();
      if (act) {
#pragma unroll
        for (int ch = 0; ch < 2; ++ch) {
          const int swcol = (ch * 16 + hl0q) ^ SWZ(row);  // 4-aligned
          f32x4 ss = (f32x4){0.f, 0.f, 0.f, 0.f};
#pragma unroll
          for (int w = 0; w < 8; ++w) ss += *(const f32x4*)&zl[w * 2048 + row * 32 + swcol];
#pragma unroll
          for (int el = 0; el < 4; ++el) gsum[el][P * 2 + ch] = ss[el];
        }
      }
    }

    // ---- gates + state update (i,f,g,o); 8B coherent publish (r10-verified) ----
    if (act) {
      const f32x4 cp = *(const f32x4*)c32p;
      f32x4 cn, hn;
#pragma unroll
      for (int el = 0; el < 4; ++el) {
        const float zi = gsum[el][0] + brg[0][el];
        const float zf = gsum[el][1] + brg[1][el];
        const float zg = gsum[el][2] + brg[2][el];
        const float zo = gsum[el][3] + brg[3][el];
        cn[el] = sigf(zf) * cp[el] + sigf(zi) * tanh_(zg);
        hn[el] = sigf(zo) * tanh_(cn[el]);
      }
      *(f32x4*)c32p = cn;
      union { f16 h[4]; u64 u; } ph, pc;
#pragma unroll
      for (int el = 0; el < 4; ++el) { ph.h[el] = (f16)hn[el]; pc.h[el] = (f16)cn[el]; }
      const int slot = (t + 1) & 3;
      __hip_atomic_store(hP + (size_t)slot * 16384 + g64, ph.u,
                         __ATOMIC_RELAXED, __HIP_MEMORY_SCOPE_AGENT);
      if (j < 3)
        __hip_atomic_store(cP + (size_t)slot * 16384 + g64, pc.u,
                           __ATOMIC_RELAXED, __HIP_MEMORY_SCOPE_AGENT);
      if (j == 3 && t == TT - 1) *(f32x4*)&out[(row << 10) + hu0] = cn;
    }

    // ---- publish: drain stores + zl reads, barrier, single epoch STORE ----
    asm volatile("s_waitcnt vmcnt(0)" ::: "memory");
    __syncthreads();
    if (tid == 0)
      __hip_atomic_store(&g_ep[j][s], (unsigned)(t + 1),
                         __ATOMIC_RELAXED, __HIP_MEMORY_SCOPE_AGENT);
  }
}

extern "C" void kernel_launch(void* const* d_in, const int* in_sizes, int n_in,
                              void* d_out, int out_size, void* d_ws, size_t ws_size,
                              hipStream_t stream) {
  const float* inp  = (const float*)d_in[0];
  const float* W    = (const float*)d_in[1];
  const float* U    = (const float*)d_in[2];
  const float* bias = (const float*)d_in[3];
  float* out = (float*)d_out;
  k_init<<<256, 256, 0, stream>>>();
  k_pack_in<<<4096, 512, 0, stream>>>(inp);
  k_main<<<NWG, 512, 0, stream>>>(W, U, bias, out);
}

// Round 15
// 2015.051 us; speedup vs baseline: 1.4784x; 1.1951x over previous
//
#include <hip/hip_runtime.h>

#define TT 128
#define BB 64
#define HH 1024
#define LL 4
#define NWG 256

typedef _Float16 f16;
typedef __attribute__((ext_vector_type(4))) _Float16 f16x4;
typedef __attribute__((ext_vector_type(8))) _Float16 f16x8;
typedef __attribute__((ext_vector_type(4))) float f32x4;
typedef unsigned long long u64;

// ---------------- persistent device buffers ----------------
// Fragment layout for a [64 rows x 1024 k] fp16 tensor (HW-verified r1/r4/r6/r7):
//   flat = ((rg*32 + ktp)*64 + lane)*8 + e
//   rg = row>>4, ktp = k>>5, lane = ((k>>2)&3)<<4 | (row&15), e = ((k>>4)&1)<<2 | (k&3)
__device__ __align__(16) f16 g_in16[TT][65536];        // inputs, frag layout per t
// 8-deep rotating state slots (t&7): slot (t+1)&7 holds post-step-t state.
// Producers publish with device-scope atomic stores; consumers read with
// device-scope atomic loads (bypass stale L1/L2). NO cache-wide fences (r10-proven).
// 8 slots (vs r10's 4) push the anti-overwrite wait target to t-6, which is
// satisfied ~5 ticks in advance -> the 64-wide poll exits on first read.
__device__ __align__(16) f16 g_c16[LL][8][65536];      // cell state (feeds next layer)
__device__ __align__(16) f16 g_h16[LL][8][65536];      // hidden state (U-matmul input)
__device__ __align__(16) float g_c32[LL][BB][HH];      // cell state master f32 (WG-private)
// per-producer epoch: g_ep[j][s] = t+1 after WG (j,s) finished step t (atomic STORE).
__device__ unsigned g_ep[LL][64];

// ---------------- init: zero h slot 0 + epochs + c32 ----------------
__global__ void k_init() {
  unsigned tid = blockIdx.x * blockDim.x + threadIdx.x;
  unsigned n = gridDim.x * blockDim.x;
  float* c32 = &g_c32[0][0][0];
  for (unsigned i = tid; i < LL * BB * HH; i += n) c32[i] = 0.f;
  for (unsigned i = tid; i < LL * 32768; i += n) {
    int jj = i >> 15, q = i & 32767;
    ((unsigned*)&g_h16[jj][0][0])[q] = 0u;   // h(0) = 0 in slot 0
  }
  unsigned* pe = &g_ep[0][0];
  for (unsigned i = tid; i < LL * 64; i += n) pe[i] = 0u;
}

// ---------------- pack inputs f32 -> fp16 fragment layout (verified) ----------------
__global__ void k_pack_in(const float* __restrict__ inp) {
  int tid = blockIdx.x * blockDim.x + threadIdx.x;
  int t = tid >> 14, q = tid & 16383;
  int row = q >> 8, hu = (q & 255) << 2;
  const float4 x = *(const float4*)(inp + ((size_t)t << 16) + (row << 10) + hu);
  int rg = row >> 4, ktp = hu >> 5;
  int ln = (((hu >> 2) & 3) << 4) | (row & 15);
  int e0 = ((hu >> 4) & 1) << 2;
  f16x4 v = {(f16)x.x, (f16)x.y, (f16)x.z, (f16)x.w};
  *(f16x4*)&g_in16[t][(((rg * 32 + ktp) * 64 + ln) << 3) + e0] = v;
}

// ---------------- helpers ----------------
__device__ __forceinline__ float sigf(float x) { return 1.f / (1.f + __expf(-x)); }
__device__ __forceinline__ float tanh_(float x) {
  float q = __expf(-2.f * fabsf(x));
  return copysignf((1.f - q) / (1.f + q), x);
}
__device__ __forceinline__ f16x4 lo8(f16x8 v) { return __builtin_shufflevector(v, v, 0, 1, 2, 3); }
__device__ __forceinline__ f16x4 hi8(f16x8 v) { return __builtin_shufflevector(v, v, 4, 5, 6, 7); }
// lane-parallel wait: lane l polls its own producer-epoch slot; exit when all >= target
__device__ __forceinline__ void waitep(const unsigned* ep, unsigned target) {
  for (;;) {
    unsigned e = __hip_atomic_load(ep, __ATOMIC_RELAXED, __HIP_MEMORY_SCOPE_AGENT);
    if (__all((int)(e >= target))) break;
    __builtin_amdgcn_s_sleep(1);
  }
}
// coherent (device-scope) 16B state load: two u64 atomic loads, bypass stale L1/L2,
// vmcnt-tracked by the compiler (pipelines normally). coh is wave-uniform. (r6-proven)
__device__ __forceinline__ f16x8 ldA(const f16* p, bool coh) {
  if (coh) {
    const u64* q = (const u64*)p;
    union { u64 v[2]; f16x8 h; } u;
    u.v[0] = __hip_atomic_load(q,     __ATOMIC_RELAXED, __HIP_MEMORY_SCOPE_AGENT);
    u.v[1] = __hip_atomic_load(q + 1, __ATOMIC_RELAXED, __HIP_MEMORY_SCOPE_AGENT);
    return u.h;
  }
  return *(const f16x8*)p;
}

#define MFMA16(A_, B_, C_) __builtin_amdgcn_mfma_f32_16x16x16f16(A_, B_, C_, 0, 0, 0)
#define SWZ(r) ((((r) & 4) << 2) ^ (((r) & 3) << 3))

// Decomposition (r7/r10-proven): WG (j,s) owns 64 rows x 64 gate-cols. Wave w:
// mat = w>>2 (0: x@W, 1: h@U), K-quarter kq = w&3; Wr[32] f16x8 = 128 VGPRs,
// disjoint 32 KB A slice, depth-1 reg ring (the only non-spilling depth; r13 spilled).
// r15: ping-pong zl buffers (128 KiB LDS) -> 3 barriers/stage instead of 5:
//   wA -> BAR -> {rA || wB} -> BAR -> rB+epilogue -> drain+BAR -> epoch store.
// (wA needs no entry barrier: prev stage's rA finished before its publish barrier.)
__global__ __launch_bounds__(512, 2) void k_main(const float* __restrict__ W,
                                                 const float* __restrict__ U,
                                                 const float* __restrict__ bias,
                                                 float* __restrict__ out) {
  const int j = blockIdx.x >> 6, s = blockIdx.x & 63;
  const int tid = threadIdx.x, lane = tid & 63, wv = tid >> 6;
  const int mat = wv >> 2, kq = wv & 3;
  __shared__ float zl[2][16384];  // ping-pong: [phase][wave][row][32 colhalf], 128 KiB

  // ---- one-time weight gather f32 -> fp16 regs (r4-verified) ----
  const float* src = (mat ? U : W) + (size_t)j * (HH * 4 * HH);
  const int colb = s * 16 + (lane & 15);
  const int kb0 = kq * 256 + ((lane >> 4) << 2);
  f16x8 Wr[32];
#pragma unroll
  for (int kk = 0; kk < 16; ++kk)
#pragma unroll
    for (int cfp = 0; cfp < 2; ++cfp) {
      f16x8 v;
#pragma unroll
      for (int hf = 0; hf < 2; ++hf)
#pragma unroll
        for (int e = 0; e < 4; ++e)
          v[hf * 4 + e] = (f16)src[(size_t)(kb0 + kk * 16 + e) * 4096 + (cfp * 2 + hf) * 1024 + colb];
      Wr[kk * 2 + cfp] = v;
    }

  // ---- per-thread epilogue constants (r10-verified) ----
  const bool act = tid < 256;
  const int row = (tid & 255) >> 2;        // 0..63
  const int hl0q = (tid & 3) * 4;          // 0,4,8,12
  const int hu0 = s * 16 + hl0q;           // 4-aligned
  f32x4 brg[4];
#pragma unroll
  for (int g = 0; g < 4; ++g) brg[g] = *(const f32x4*)&bias[j * 4096 + g * 1024 + hu0];
  const int grp = (((row >> 4) * 32 + (hu0 >> 5)) * 64 +
                   ((((hu0 >> 2) & 3) << 4) | (row & 15)));
  const int e0 = ((hu0 >> 4) & 1) << 2;
  const int g64 = grp * 2 + (e0 >> 2);     // u64 index within a slot (slot = 16384 u64)
  u64* const hP = (u64*)&g_h16[j][0][0];
  u64* const cP = (u64*)&g_c16[j][0][0];
  float* const c32p = &g_c32[j][row][hu0];
  const int ktp0 = kq * 8;
  const bool coh = mat || (j > 0);  // in16 is pre-launch constant -> plain loads ok
  const unsigned* epX = (j > 0) ? &g_ep[j - 1][kq * 16 + (lane & 15)] : nullptr;
  const unsigned* epH = &g_ep[j][kq * 16 + (lane & 15)];
  const unsigned* epA = (j < 3) ? &g_ep[j + 1][lane] : nullptr;  // anti-overwrite

  for (int t = 0; t < TT; ++t) {
    // ---- per-wave dependency waits (no fences, no RMW flags; r10-proven) ----
    if (mat == 0) {
      if (j > 0) waitep(epX, (unsigned)(t + 1));       // layer below finished step t
    } else {
      if (t > 0) waitep(epH, (unsigned)t);             // own layer finished step t-1
      if (j < 3 && t >= 7) waitep(epA, (unsigned)(t - 6));  // slot reuse: ~pre-satisfied
    }
    asm volatile("" ::: "memory");  // forbid hoisting A loads above the polls

    const f16* Ab = mat ? &g_h16[j][t & 7][0]
                        : (j ? &g_c16[j - 1][(t + 1) & 7][0] : &g_in16[t][0]);
    f16x8 a[2][4];
#pragma unroll
    for (int rf = 0; rf < 4; ++rf)
      a[0][rf] = ldA(Ab + (rf * 32 + ktp0) * 512 + lane * 8, coh);

    f32x4 acc[4][4];
#pragma unroll
    for (int rf = 0; rf < 4; ++rf)
#pragma unroll
      for (int cf = 0; cf < 4; ++cf) acc[rf][cf] = (f32x4){0.f, 0.f, 0.f, 0.f};

#pragma unroll
    for (int kc = 0; kc < 8; ++kc) {
      if (kc < 7) {
#pragma unroll
        for (int rf = 0; rf < 4; ++rf)
          a[(kc + 1) & 1][rf] = ldA(Ab + (rf * 32 + ktp0 + kc + 1) * 512 + lane * 8, coh);
      }
#pragma unroll
      for (int hf = 0; hf < 2; ++hf) {
        f16x4 a4[4];
#pragma unroll
        for (int rf = 0; rf < 4; ++rf)
          a4[rf] = hf ? hi8(a[kc & 1][rf]) : lo8(a[kc & 1][rf]);
#pragma unroll
        for (int cf = 0; cf < 4; ++cf) {
          const f16x8 wreg = Wr[(kc * 2 + hf) * 2 + (cf >> 1)];
          const f16x4 b4 = (cf & 1) ? hi8(wreg) : lo8(wreg);
#pragma unroll
          for (int rf = 0; rf < 4; ++rf) acc[rf][cf] = MFMA16(a4[rf], b4, acc[rf][cf]);
        }
      }
    }

    // ---- ping-pong 8-wave reduction: 3 barriers total (r15) ----
    float gsum[4][4];  // [el 0..3][gate]
    // phase A writes (gates 0,1) -> zl[0]; no entry barrier needed (see header note)
#pragma unroll
    for (int rf = 0; rf < 4; ++rf)
#pragma unroll
      for (int ch = 0; ch < 2; ++ch)
#pragma unroll
        for (int ri = 0; ri < 4; ++ri) {
          const int rr = rf * 16 + ((lane >> 4) << 2) + ri;
          const int c2 = ch * 16 + (lane & 15);
          zl[0][wv * 2048 + rr * 32 + (c2 ^ SWZ(rr))] = acc[rf][ch][ri];
        }
    __syncthreads();  // BAR1: phase-A visible; joins x/h waves
    // phase B writes (gates 2,3) -> zl[1], overlapping phase-A reads
#pragma unroll
    for (int rf = 0; rf < 4; ++rf)
#pragma unroll
      for (int ch = 0; ch < 2; ++ch)
#pragma unroll
        for (int ri = 0; ri < 4; ++ri) {
          const int rr = rf * 16 + ((lane >> 4) << 2) + ri;
          const int c2 = ch * 16 + (lane & 15);
          zl[1][wv * 2048 + rr * 32 + (c2 ^ SWZ(rr))] = acc[rf][2 + ch][ri];
        }
    if (act) {
#pragma unroll
      for (int ch = 0; ch < 2; ++ch) {
        const int swcol = (ch * 16 + hl0q) ^ SWZ(row);  // 4-aligned
        f32x4 ss = (f32x4){0.f, 0.f, 0.f, 0.f};
#pragma unroll
        for (int w = 0; w < 8; ++w) ss += *(const f32x4*)&zl[0][w * 2048 + row * 32 + swcol];
#pragma unroll
        for (int el = 0; el < 4; ++el) gsum[el][ch] = ss[el];
      }
    }
    __syncthreads();  // BAR2: phase-B visible; phase-A reads done
    if (act) {
#pragma unroll
      for (int ch = 0; ch < 2; ++ch) {
        const int swcol = (ch * 16 + hl0q) ^ SWZ(row);
        f32x4 ss = (f32x4){0.f, 0.f, 0.f, 0.f};
#pragma unroll
        for (int w = 0; w < 8; ++w) ss += *(const f32x4*)&zl[1][w * 2048 + row * 32 + swcol];
#pragma unroll
        for (int el = 0; el < 4; ++el) gsum[el][2 + ch] = ss[el];
      }

      // ---- gates + state update (i,f,g,o); 8B coherent publish (r10-verified) ----
      const f32x4 cp = *(const f32x4*)c32p;
      f32x4 cn, hn;
#pragma unroll
      for (int el = 0; el < 4; ++el) {
        const float zi = gsum[el][0] + brg[0][el];
        const float zf = gsum[el][1] + brg[1][el];
        const float zg = gsum[el][2] + brg[2][el];
        const float zo = gsum[el][3] + brg[3][el];
        cn[el] = sigf(zf) * cp[el] + sigf(zi) * tanh_(zg);
        hn[el] = sigf(zo) * tanh_(cn[el]);
      }
      *(f32x4*)c32p = cn;
      union { f16 h[4]; u64 u; } ph, pc;
#pragma unroll
      for (int el = 0; el < 4; ++el) { ph.h[el] = (f16)hn[el]; pc.h[el] = (f16)cn[el]; }
      const int slot = (t + 1) & 7;
      __hip_atomic_store(hP + (size_t)slot * 16384 + g64, ph.u,
                         __ATOMIC_RELAXED, __HIP_MEMORY_SCOPE_AGENT);
      if (j < 3)
        __hip_atomic_store(cP + (size_t)slot * 16384 + g64, pc.u,
                           __ATOMIC_RELAXED, __HIP_MEMORY_SCOPE_AGENT);
      if (j == 3 && t == TT - 1) *(f32x4*)&out[(row << 10) + hu0] = cn;
    }

    // ---- publish: drain device-scope stores, barrier, single epoch STORE ----
    asm volatile("s_waitcnt vmcnt(0)" ::: "memory");
    __syncthreads();  // BAR3: all stores drained; zl[1] reads done
    if (tid == 0)
      __hip_atomic_store(&g_ep[j][s], (unsigned)(t + 1),
                         __ATOMIC_RELAXED, __HIP_MEMORY_SCOPE_AGENT);
  }
}

extern "C" void kernel_launch(void* const* d_in, const int* in_sizes, int n_in,
                              void* d_out, int out_size, void* d_ws, size_t ws_size,
                              hipStream_t stream) {
  const float* inp  = (const float*)d_in[0];
  const float* W    = (const float*)d_in[1];
  const float* U    = (const float*)d_in[2];
  const float* bias = (const float*)d_in[3];
  float* out = (float*)d_out;
  k_init<<<256, 256, 0, stream>>>();
  k_pack_in<<<4096, 512, 0, stream>>>(inp);
  k_main<<<NWG, 512, 0, stream>>>(W, U, bias, out);
}